// Round 6
// baseline (295.116 us; speedup 1.0000x reference)
//
#include <hip/hip_runtime.h>

#define HW 1024
#define NB 8
#define LPT 16            // elements per lane; 64 lanes * 16 = 1024 row elements
#define CHUNK 8           // output rows owned per workgroup
#define NCH (HW / CHUNK)  // 128 chunks
#define WARM 64           // warm-start window (truncation ~ rho^WARM)

__device__ __forceinline__ float shfl_up1(float v)  { return __shfl_up(v, 1, 64); }
__device__ __forceinline__ float shfl_dn1(float v)  { return __shfl_down(v, 1, 64); }

// Register-array layouts (per lane, base = lane*16):
//   X[32]: x at positions base-8 .. base+23   (X[j] = x[base+j-8]); row-pad zeros.
//   S[28]: s at positions base-6 .. base+21   (S[n] = s[base+n-6])
//   U[24]: u at positions base-4 .. base+19   (U[n] = u[base+n-4])
// Each step computes s on [-4,20) (24 vals) and u on [-2,18) (20 vals)
// REDUNDANTLY, so u-conv needs no shuffled s; per-step cross-lane traffic is
// only the +/-2 extension of each state (2 shfl groups, latency hidden under
// the following conv). x halos are loaded directly from global (no shfl).

// Load row T into XD (aligned float4s; address clamped at row ends, pad->0).
#define LOADX(XD, T)                                                         \
    {                                                                        \
        const float* rp  = Ib + (size_t)(T) * HW + base;                     \
        const float* lpl = lo ? rp : rp - 8;                                 \
        const float* lpr = hi ? rp : rp + 16;                                \
        float4 va = *(const float4*)(lpl);                                   \
        float4 vb = *(const float4*)(lpl + 4);                               \
        XD[0] = lo ? 0.f : va.x; XD[1] = lo ? 0.f : va.y;                    \
        XD[2] = lo ? 0.f : va.z; XD[3] = lo ? 0.f : va.w;                    \
        XD[4] = lo ? 0.f : vb.x; XD[5] = lo ? 0.f : vb.y;                    \
        XD[6] = lo ? 0.f : vb.z; XD[7] = lo ? 0.f : vb.w;                    \
        _Pragma("unroll")                                                    \
        for (int q = 0; q < 4; ++q)                                          \
            *(float4*)&XD[8 + 4 * q] = *(const float4*)(rp + 4 * q);         \
        float4 vc = *(const float4*)(lpr);                                   \
        float4 vd = *(const float4*)(lpr + 4);                               \
        XD[24] = hi ? 0.f : vc.x; XD[25] = hi ? 0.f : vc.y;                  \
        XD[26] = hi ? 0.f : vc.z; XD[27] = hi ? 0.f : vc.w;                  \
        XD[28] = hi ? 0.f : vd.x; XD[29] = hi ? 0.f : vd.y;                  \
        XD[30] = hi ? 0.f : vd.z; XD[31] = hi ? 0.f : vd.w;                  \
    }

// One recurrence step at time T. Reads XC (row T), SC, UC; writes SN, UN;
// prefetches row T+2 into XC (XC is dead after the s-conv reads it).
#define STEP(IS_PRE, T, XC, SC, SN, UN, UC)                                  \
    {                                                                        \
        const int t_ = (T);                                                  \
        /* s-conv on extended range: SN[m+2], m in [0,24), pos = m-4 */      \
        _Pragma("unroll")                                                    \
        for (int m = 0; m < 24; ++m) {                                       \
            float acc;                                                       \
            if (IS_PRE) {                                                    \
                acc = pB1;                                                   \
                _Pragma("unroll")                                            \
                for (int k = 0; k < 5; ++k) acc += P1[k] * XC[m + k + 2];    \
            } else {                                                         \
                acc = cB1;                                                   \
                _Pragma("unroll")                                            \
                for (int k = 0; k < 5; ++k) acc += A1[k] * SC[m + k];        \
                _Pragma("unroll")                                            \
                for (int k = 0; k < 5; ++k) acc += B1[k] * XC[m + k + 2];    \
            }                                                                \
            const int n = m + 2;                                             \
            SN[n] = ((lo && n < 6) || (hi && n >= 22)) ? 0.f : acc;          \
        }                                                                    \
        /* s +/-2 extension: one shfl group, hidden under u-conv */          \
        {                                                                    \
            float a = shfl_up1(SN[16]), c = shfl_up1(SN[17]);                \
            float d = shfl_dn1(SN[10]), e = shfl_dn1(SN[11]);                \
            SN[0]  = lo ? 0.f : a;  SN[1]  = lo ? 0.f : c;                   \
            SN[26] = hi ? 0.f : d;  SN[27] = hi ? 0.f : e;                   \
        }                                                                    \
        /* prefetch row T+2 into XC (WAR: loads ordered after s-conv) */     \
        if (t_ + 2 < T1) { LOADX(XC, t_ + 2); }                              \
        /* u-conv: UN[n], n in [2,22), pos = n-4; reads SN (no shfl dep) */  \
        _Pragma("unroll")                                                    \
        for (int n = 2; n < 22; ++n) {                                       \
            float acc;                                                       \
            if (IS_PRE) {                                                    \
                acc = pB2;                                                   \
                _Pragma("unroll")                                            \
                for (int k = 0; k < 5; ++k) acc += P2[k] * SN[n + k];        \
            } else {                                                         \
                acc = cB2;                                                   \
                _Pragma("unroll")                                            \
                for (int k = 0; k < 5; ++k) acc += A2[k] * UC[n + k - 2];    \
                _Pragma("unroll")                                            \
                for (int k = 0; k < 5; ++k) acc += B2[k] * SN[n + k];        \
            }                                                                \
            UN[n] = ((lo && n < 4) || (hi && n >= 20)) ? 0.f : acc;          \
        }                                                                    \
        /* u +/-2 extension: hidden under next step's s-conv */              \
        {                                                                    \
            float a = shfl_up1(UN[16]), c = shfl_up1(UN[17]);                \
            float d = shfl_dn1(UN[6]),  e = shfl_dn1(UN[7]);                 \
            UN[0]  = lo ? 0.f : a;  UN[1]  = lo ? 0.f : c;                   \
            UN[22] = hi ? 0.f : d;  UN[23] = hi ? 0.f : e;                   \
        }                                                                    \
        /* store owned rows: positions 0..15 = UN[4..20) */                  \
        if (t_ >= T0) {                                                      \
            _Pragma("unroll")                                                \
            for (int q = 0; q < 4; ++q) {                                    \
                float4 v;                                                    \
                v.x = UN[4 + 4 * q]; v.y = UN[5 + 4 * q];                    \
                v.z = UN[6 + 4 * q]; v.w = UN[7 + 4 * q];                    \
                *(float4*)(Ob + (size_t)t_ * HW + base + 4 * q) = v;         \
            }                                                                \
        }                                                                    \
    }

// One wave per (batch, chunk). Chunk owns rows [T0, T0+CHUNK); warm-starts
// from zero state at g0 = max(0, T0-WARM); g0==0 chunks are exact (pre path).
__global__ __launch_bounds__(64, 1) void scan_pair_wave(
    const float* __restrict__ I, float* __restrict__ O,
    const float* __restrict__ pw1, const float* __restrict__ pb1,
    const float* __restrict__ pw2, const float* __restrict__ pb2,
    const float* __restrict__ cw1, const float* __restrict__ cb1,
    const float* __restrict__ cw2, const float* __restrict__ cb2,
    int toff, int tstr)
{
    const int b     = blockIdx.y;
    const int chunk = blockIdx.x;
    const int T0    = chunk * CHUNK;
    const int T1    = T0 + CHUNK;
    const int g0    = (T0 - WARM > 0) ? (T0 - WARM) : 0;

    const int lane = threadIdx.x;           // 0..63
    const int base = lane * LPT;
    const bool lo = (lane == 0), hi = (lane == 63);

    float P1[5], P2[5], A1[5], B1[5], A2[5], B2[5];
#pragma unroll
    for (int k = 0; k < 5; ++k) {
        P1[k] = pw1[toff + k * tstr];
        P2[k] = pw2[toff + k * tstr];
        A1[k] = cw1[toff + k * tstr];
        B1[k] = cw1[25 + toff + k * tstr];
        A2[k] = cw2[toff + k * tstr];
        B2[k] = cw2[25 + toff + k * tstr];
    }
    const float pB1 = pb1[0], pB2 = pb2[0], cB1 = cb1[0], cB2 = cb2[0];

    const float* Ib = I + (size_t)b * HW * HW;
    float*       Ob = O + (size_t)b * HW * HW;

    float xA[32], xB[32], sA[28], sB[28], uA[24], uB[24];
#pragma unroll
    for (int i = 0; i < 28; ++i) sA[i] = 0.f;
#pragma unroll
    for (int i = 0; i < 24; ++i) uA[i] = 0.f;

    LOADX(xA, g0);
    LOADX(xB, g0 + 1);

    if (g0 == 0) {                       // exact start: pre-conv at t=0
        STEP(1, 0, xA, sA, sB, uB, uA);  // writes sB,uB; prefetch row2->xA
        int t;
        for (t = 1; t + 1 < T1; t += 2) {
            STEP(0, t,     xB, sB, sA, uA, uB);
            STEP(0, t + 1, xA, sA, sB, uB, uA);
        }
        STEP(0, T1 - 1, xB, sB, sA, uA, uB);   // final odd step (always owned)
    } else {                             // warm start: depth = WARM+CHUNK (even)
        for (int t = g0; t + 1 < T1; t += 2) {
            STEP(0, t,     xA, sA, sB, uB, uA);
            STEP(0, t + 1, xB, sB, sA, uA, uB);
        }
    }
}

// out[b][c][r] = in[b][HW-1-r][c]  (transpose + reversal of the scan axis)
__global__ void transposeR_kernel(const float* __restrict__ in, float* __restrict__ out)
{
    __shared__ float tile[32][33];
    const int b  = blockIdx.z;
    const int r0 = blockIdx.y * 32;
    const int c0 = blockIdx.x * 32;
    const int tx = threadIdx.x, ty = threadIdx.y;
    const float* inb  = in  + (size_t)b * HW * HW;
    float*       outb = out + (size_t)b * HW * HW;

#pragma unroll
    for (int i = ty; i < 32; i += 8)
        tile[i][tx] = inb[(size_t)(HW - 1 - (r0 + i)) * HW + c0 + tx];
    __syncthreads();
#pragma unroll
    for (int i = ty; i < 32; i += 8)
        outb[(size_t)(c0 + i) * HW + r0 + tx] = tile[tx][i];
}

extern "C" void kernel_launch(void* const* d_in, const int* in_sizes, int n_in,
                              void* d_out, int out_size, void* d_ws, size_t ws_size,
                              hipStream_t stream)
{
    const float* x      = (const float*)d_in[0];
    const float* pre1_w = (const float*)d_in[1];
    const float* pre1_b = (const float*)d_in[2];
    const float* pre2_w = (const float*)d_in[3];
    const float* pre2_b = (const float*)d_in[4];
    const float* pre3_w = (const float*)d_in[5];
    const float* pre3_b = (const float*)d_in[6];
    const float* pre4_w = (const float*)d_in[7];
    const float* pre4_b = (const float*)d_in[8];
    const float* c1_w   = (const float*)d_in[9];
    const float* c1_b   = (const float*)d_in[10];
    const float* c2_w   = (const float*)d_in[11];
    const float* c2_b   = (const float*)d_in[12];
    const float* c3_w   = (const float*)d_in[13];
    const float* c3_b   = (const float*)d_in[14];
    const float* c4_w   = (const float*)d_in[15];
    const float* c4_b   = (const float*)d_in[16];

    float* out = (float*)d_out;   // holds T2 mid-pipeline, then final output
    float* ws  = (float*)d_ws;    // holds U, then Z (chunked scans not in-place)

    dim3 sg(NCH, NB), sb(64);
    dim3 tg(32, 32, NB), tb(32, 8);

    // Pass 1+2 fused: scan over h, conv along w (middle-row taps off=10, str=1).
    scan_pair_wave<<<sg, sb, 0, stream>>>(
        x, ws, pre1_w, pre1_b, pre2_w, pre2_b, c1_w, c1_b, c2_w, c2_b, 10, 1);

    // T2[b][w][h] = U[b][H-1-h][w]
    transposeR_kernel<<<tg, tb, 0, stream>>>(ws, out);

    // Pass 3+4 fused: scan over w, conv along h (middle-col taps off=2, str=5).
    scan_pair_wave<<<sg, sb, 0, stream>>>(
        out, ws, pre3_w, pre3_b, pre4_w, pre4_b, c3_w, c3_b, c4_w, c4_b, 2, 5);

    // out[b][h][w] = Z[b][W-1-w][h]
    transposeR_kernel<<<tg, tb, 0, stream>>>(ws, out);
}

// Round 7
// 214.113 us; speedup vs baseline: 1.3783x; 1.3783x over previous
//
#include <hip/hip_runtime.h>

#define HW 1024
#define NB 8
#define LPT 16            // elements per lane; 64 lanes * 16 = 1024 row elements
#define CHUNK 8           // output rows owned per workgroup
#define NCH (HW / CHUNK)  // 128 chunks
#define WARM 64           // warm-start window (truncation ~ rho^WARM)

__device__ __forceinline__ float shfl_up1(float v)  { return __shfl_up(v, 1, 64); }
__device__ __forceinline__ float shfl_dn1(float v)  { return __shfl_down(v, 1, 64); }

// Software-pipelined fused two-state scan. Extended arrays xe/se/ue[20]:
// e[2+i] = value at position base+i (i=0..15); e[0..1], e[18..19] are +/-2
// halos. Iteration t computes u_t (from u_{t-1}, s_t) and s_{t+1} (from s_t,
// x_{t+1}) -- INDEPENDENT convs -- then one batched 12-bpermute shfl group
// (s-ext, u-ext, next-x halos). Row t+2 prefetch issued at iteration top.
//
// One wave per (batch, chunk); chunk owns rows [T0,T0+CHUNK), warm-starts
// from zero state at g0 = max(0, T0-WARM); g0==0 chunks are exact (pre path).
// Grid is (NB, NCH): linear wg id = b + 8*chunk -> id%8 = b -> all chunks of
// batch b share XCD b's L2 (4 MB = one batch image) -> warmup re-reads are
// L2 hits, HBM fetch ~= compulsory 32 MB.
__global__ __launch_bounds__(64, 1) void scan_pair_wave(
    const float* __restrict__ I, float* __restrict__ O,
    const float* __restrict__ pw1, const float* __restrict__ pb1,
    const float* __restrict__ pw2, const float* __restrict__ pb2,
    const float* __restrict__ cw1, const float* __restrict__ cb1,
    const float* __restrict__ cw2, const float* __restrict__ cb2,
    int toff, int tstr)
{
    const int b     = blockIdx.x;        // batch -> XCD (linear id % 8 == b)
    const int chunk = blockIdx.y;
    const int T0 = chunk * CHUNK, T1 = T0 + CHUNK;
    const int g0 = (T0 - WARM > 0) ? (T0 - WARM) : 0;

    const int lane = threadIdx.x;        // 0..63
    const int base = lane * LPT;
    const bool lo = (lane == 0), hi = (lane == 63);

    float P1[5], P2[5], A1[5], B1[5], A2[5], B2[5];
#pragma unroll
    for (int k = 0; k < 5; ++k) {
        P1[k] = pw1[toff + k * tstr];
        P2[k] = pw2[toff + k * tstr];
        A1[k] = cw1[toff + k * tstr];
        B1[k] = cw1[25 + toff + k * tstr];
        A2[k] = cw2[toff + k * tstr];
        B2[k] = cw2[25 + toff + k * tstr];
    }
    const float pB1 = pb1[0], pB2 = pb2[0], cB1 = cb1[0], cB2 = cb2[0];

    const float* Ib = I + (size_t)b * HW * HW;
    float*       Ob = O + (size_t)b * HW * HW;

    float xe[20], se[20], ue[20], sn[16], un[16];
    float4 xp[4];

#define LOADROW(T)                                                          \
    {                                                                       \
        const int tr_ = (T) < HW ? (T) : (HW - 1);                          \
        const float* rp_ = Ib + (size_t)tr_ * HW + base;                    \
        xp[0] = ((const float4*)rp_)[0];                                    \
        xp[1] = ((const float4*)rp_)[1];                                    \
        xp[2] = ((const float4*)rp_)[2];                                    \
        xp[3] = ((const float4*)rp_)[3];                                    \
    }

#define UNPACKX(XA, XB, XC, XD)                                             \
    {                                                                       \
        xe[2]  = xp[0].x; xe[3]  = xp[0].y; xe[4]  = xp[0].z; xe[5]  = xp[0].w; \
        xe[6]  = xp[1].x; xe[7]  = xp[1].y; xe[8]  = xp[1].z; xe[9]  = xp[1].w; \
        xe[10] = xp[2].x; xe[11] = xp[2].y; xe[12] = xp[2].z; xe[13] = xp[2].w; \
        xe[14] = xp[3].x; xe[15] = xp[3].y; xe[16] = xp[3].z; xe[17] = xp[3].w; \
        xe[0]  = lo ? 0.f : (XA); xe[1]  = lo ? 0.f : (XB);                 \
        xe[18] = hi ? 0.f : (XC); xe[19] = hi ? 0.f : (XD);                 \
    }

    // ---------------- prologue ----------------
#pragma unroll
    for (int i = 0; i < 20; ++i) ue[i] = 0.f;

    LOADROW(g0);
    {
        float xa = shfl_up1(xp[3].z), xb = shfl_up1(xp[3].w);
        float xc = shfl_dn1(xp[0].x), xd = shfl_dn1(xp[0].y);
        UNPACKX(xa, xb, xc, xd);
    }
    if (g0 == 0) {      // exact start: s_0 = P1 (*) x_0 + pB1
#pragma unroll
        for (int i = 0; i < 16; ++i) {
            float acc = pB1;
#pragma unroll
            for (int k = 0; k < 5; ++k) acc += P1[k] * xe[i + k];
            sn[i] = acc;
        }
    } else {            // warm start (zero state): s_g0 = B1 (*) x_g0 + cB1
#pragma unroll
        for (int i = 0; i < 16; ++i) {
            float acc = cB1;
#pragma unroll
            for (int k = 0; k < 5; ++k) acc += B1[k] * xe[i + k];
            sn[i] = acc;
        }
    }
    LOADROW(g0 + 1);
    {
        float sa = shfl_up1(sn[14]), sb = shfl_up1(sn[15]);
        float sc = shfl_dn1(sn[0]),  sd = shfl_dn1(sn[1]);
        float xa = shfl_up1(xp[3].z), xb = shfl_up1(xp[3].w);
        float xc = shfl_dn1(xp[0].x), xd = shfl_dn1(xp[0].y);
#pragma unroll
        for (int i = 0; i < 16; ++i) se[2 + i] = sn[i];
        se[0]  = lo ? 0.f : sa; se[1]  = lo ? 0.f : sb;
        se[18] = hi ? 0.f : sc; se[19] = hi ? 0.f : sd;
        UNPACKX(xa, xb, xc, xd);
    }

    // ---------------- main loop: t = g0 .. T1-2 ----------------
    // Invariants at entry: xe = row t+1 (ext), se = s_t (ext), ue = u_{t-1} (ext).
    for (int t = g0; t < T1 - 1; ++t) {
        LOADROW(t + 2);   // issued early; vmcnt-waited at the shfl group below

        // s_{t+1} = A1 (*) s_t + B1 (*) x_{t+1} + cB1
#pragma unroll
        for (int i = 0; i < 16; ++i) {
            float acc = cB1;
#pragma unroll
            for (int k = 0; k < 5; ++k) acc += A1[k] * se[i + k];
#pragma unroll
            for (int k = 0; k < 5; ++k) acc += B1[k] * xe[i + k];
            sn[i] = acc;
        }
        // u_t = A2 (*) u_{t-1} + B2 (*) s_t + cB2   (t==0: P2 (*) s_0 + pB2)
        if (t == 0) {
#pragma unroll
            for (int i = 0; i < 16; ++i) {
                float acc = pB2;
#pragma unroll
                for (int k = 0; k < 5; ++k) acc += P2[k] * se[i + k];
                un[i] = acc;
            }
        } else {
#pragma unroll
            for (int i = 0; i < 16; ++i) {
                float acc = cB2;
#pragma unroll
                for (int k = 0; k < 5; ++k) acc += A2[k] * ue[i + k];
#pragma unroll
                for (int k = 0; k < 5; ++k) acc += B2[k] * se[i + k];
                un[i] = acc;
            }
        }

        // one batched cross-lane group (12 bpermutes, single wait)
        float sa = shfl_up1(sn[14]), sb = shfl_up1(sn[15]);
        float sc = shfl_dn1(sn[0]),  sd = shfl_dn1(sn[1]);
        float ua = shfl_up1(un[14]), ub = shfl_up1(un[15]);
        float uc = shfl_dn1(un[0]),  ud = shfl_dn1(un[1]);
        float xa = shfl_up1(xp[3].z), xb = shfl_up1(xp[3].w);
        float xc = shfl_dn1(xp[0].x), xd = shfl_dn1(xp[0].y);

        if (t >= T0) {    // store owned rows (overlaps the shfl wait)
#pragma unroll
            for (int q = 0; q < 4; ++q) {
                float4 v;
                v.x = un[4 * q + 0]; v.y = un[4 * q + 1];
                v.z = un[4 * q + 2]; v.w = un[4 * q + 3];
                *(float4*)(Ob + (size_t)t * HW + base + 4 * q) = v;
            }
        }

#pragma unroll
        for (int i = 0; i < 16; ++i) { se[2 + i] = sn[i]; ue[2 + i] = un[i]; }
        se[0]  = lo ? 0.f : sa; se[1]  = lo ? 0.f : sb;
        se[18] = hi ? 0.f : sc; se[19] = hi ? 0.f : sd;
        ue[0]  = lo ? 0.f : ua; ue[1]  = lo ? 0.f : ub;
        ue[18] = hi ? 0.f : uc; ue[19] = hi ? 0.f : ud;
        UNPACKX(xa, xb, xc, xd);
    }

    // ---------------- epilogue: u_{T1-1} (always owned, never t==0) ----------------
    {
#pragma unroll
        for (int i = 0; i < 16; ++i) {
            float acc = cB2;
#pragma unroll
            for (int k = 0; k < 5; ++k) acc += A2[k] * ue[i + k];
#pragma unroll
            for (int k = 0; k < 5; ++k) acc += B2[k] * se[i + k];
            un[i] = acc;
        }
#pragma unroll
        for (int q = 0; q < 4; ++q) {
            float4 v;
            v.x = un[4 * q + 0]; v.y = un[4 * q + 1];
            v.z = un[4 * q + 2]; v.w = un[4 * q + 3];
            *(float4*)(Ob + (size_t)(T1 - 1) * HW + base + 4 * q) = v;
        }
    }
#undef LOADROW
#undef UNPACKX
}

// out[b][c][r] = in[b][HW-1-r][c]  (transpose + reversal of the scan axis)
__global__ void transposeR_kernel(const float* __restrict__ in, float* __restrict__ out)
{
    __shared__ float tile[32][33];
    const int b  = blockIdx.z;
    const int r0 = blockIdx.y * 32;
    const int c0 = blockIdx.x * 32;
    const int tx = threadIdx.x, ty = threadIdx.y;
    const float* inb  = in  + (size_t)b * HW * HW;
    float*       outb = out + (size_t)b * HW * HW;

#pragma unroll
    for (int i = ty; i < 32; i += 8)
        tile[i][tx] = inb[(size_t)(HW - 1 - (r0 + i)) * HW + c0 + tx];
    __syncthreads();
#pragma unroll
    for (int i = ty; i < 32; i += 8)
        outb[(size_t)(c0 + i) * HW + r0 + tx] = tile[tx][i];
}

extern "C" void kernel_launch(void* const* d_in, const int* in_sizes, int n_in,
                              void* d_out, int out_size, void* d_ws, size_t ws_size,
                              hipStream_t stream)
{
    const float* x      = (const float*)d_in[0];
    const float* pre1_w = (const float*)d_in[1];
    const float* pre1_b = (const float*)d_in[2];
    const float* pre2_w = (const float*)d_in[3];
    const float* pre2_b = (const float*)d_in[4];
    const float* pre3_w = (const float*)d_in[5];
    const float* pre3_b = (const float*)d_in[6];
    const float* pre4_w = (const float*)d_in[7];
    const float* pre4_b = (const float*)d_in[8];
    const float* c1_w   = (const float*)d_in[9];
    const float* c1_b   = (const float*)d_in[10];
    const float* c2_w   = (const float*)d_in[11];
    const float* c2_b   = (const float*)d_in[12];
    const float* c3_w   = (const float*)d_in[13];
    const float* c3_b   = (const float*)d_in[14];
    const float* c4_w   = (const float*)d_in[15];
    const float* c4_b   = (const float*)d_in[16];

    float* out = (float*)d_out;   // holds T2 mid-pipeline, then final output
    float* ws  = (float*)d_ws;    // holds U, then Z (chunked scans not in-place)

    dim3 sg(NB, NCH), sb(64);     // blockIdx.x = batch -> XCD-local L2 reuse
    dim3 tg(32, 32, NB), tb(32, 8);

    // Pass 1+2 fused: scan over h, conv along w (middle-row taps off=10, str=1).
    scan_pair_wave<<<sg, sb, 0, stream>>>(
        x, ws, pre1_w, pre1_b, pre2_w, pre2_b, c1_w, c1_b, c2_w, c2_b, 10, 1);

    // T2[b][w][h] = U[b][H-1-h][w]
    transposeR_kernel<<<tg, tb, 0, stream>>>(ws, out);

    // Pass 3+4 fused: scan over w, conv along h (middle-col taps off=2, str=5).
    scan_pair_wave<<<sg, sb, 0, stream>>>(
        out, ws, pre3_w, pre3_b, pre4_w, pre4_b, c3_w, c3_b, c4_w, c4_b, 2, 5);

    // out[b][h][w] = Z[b][W-1-w][h]
    transposeR_kernel<<<tg, tb, 0, stream>>>(ws, out);
}

// Round 8
// 204.533 us; speedup vs baseline: 1.4429x; 1.0468x over previous
//
#include <hip/hip_runtime.h>

#define HW 1024
#define NB 8
#define LPT 16            // elements per lane; 64 lanes * 16 = 1024 row elements
#define CHUNK 4           // output rows owned per workgroup
#define NCH (HW / CHUNK)  // 256 chunks -> 2048 waves = 2 waves/SIMD
#define WARM 64           // warm-start window (truncation ~ rho^WARM)

__device__ __forceinline__ float shfl_up1(float v)  { return __shfl_up(v, 1, 64); }
__device__ __forceinline__ float shfl_dn1(float v)  { return __shfl_down(v, 1, 64); }

// Extended register arrays e[20]: e[2+i] = value at position base+i (i=0..15);
// e[0..1] / e[18..19] are +/-2 halos (zero at row ends, 'same' padding).
// Ping-pong pairs (A/B) eliminate all state-copy movs. Row loads land
// DIRECTLY in xe[2..17] (float4 stores into the register array).
// Step t: computes u_t (from u_{t-1}, s_t) and s_{t+1} (from s_t, x_{t+1})
// -- independent convs -- then one batched 12-bpermute shfl group extends
// s_{t+1}, u_t and the freshly loaded row t+2.

#define LOADX(XD, T)                                                        \
    {                                                                       \
        const int tr_ = ((T) < HW) ? (T) : (HW - 1);                        \
        const float* rp_ = Ib + (size_t)tr_ * HW + base;                    \
        *(float4*)&XD[2]  = ((const float4*)rp_)[0];                        \
        *(float4*)&XD[6]  = ((const float4*)rp_)[1];                        \
        *(float4*)&XD[10] = ((const float4*)rp_)[2];                        \
        *(float4*)&XD[14] = ((const float4*)rp_)[3];                        \
    }

// One step at time T. XC = row T+1 (ext), SC = s_T (ext), UC = u_{T-1} (ext).
// Writes SN = s_{T+1} (ext), UN = u_T (ext), XN = row T+2 (ext).
#define STEP(IS_PRE2, T, XC, XN, SC, SN, UC, UN)                            \
    {                                                                       \
        const int t_ = (T);                                                 \
        LOADX(XN, t_ + 2);                                                  \
        _Pragma("unroll")                                                   \
        for (int i = 0; i < 16; ++i) {                                      \
            float acc = cB1;                                                \
            _Pragma("unroll")                                               \
            for (int k = 0; k < 5; ++k) acc += A1[k] * SC[i + k];           \
            _Pragma("unroll")                                               \
            for (int k = 0; k < 5; ++k) acc += B1[k] * XC[i + k];           \
            SN[2 + i] = acc;                                                \
        }                                                                   \
        if (IS_PRE2) {                                                      \
            _Pragma("unroll")                                               \
            for (int i = 0; i < 16; ++i) {                                  \
                float acc = pB2;                                            \
                _Pragma("unroll")                                           \
                for (int k = 0; k < 5; ++k) acc += P2[k] * SC[i + k];       \
                UN[2 + i] = acc;                                            \
            }                                                               \
        } else {                                                            \
            _Pragma("unroll")                                               \
            for (int i = 0; i < 16; ++i) {                                  \
                float acc = cB2;                                            \
                _Pragma("unroll")                                           \
                for (int k = 0; k < 5; ++k) acc += A2[k] * UC[i + k];       \
                _Pragma("unroll")                                           \
                for (int k = 0; k < 5; ++k) acc += B2[k] * SC[i + k];       \
                UN[2 + i] = acc;                                            \
            }                                                               \
        }                                                                   \
        /* one batched cross-lane group (12 bpermutes, single wait) */      \
        float sa_ = shfl_up1(SN[16]), sb_ = shfl_up1(SN[17]);               \
        float sc_ = shfl_dn1(SN[2]),  sd_ = shfl_dn1(SN[3]);                \
        float ua_ = shfl_up1(UN[16]), ub_ = shfl_up1(UN[17]);               \
        float uc_ = shfl_dn1(UN[2]),  ud_ = shfl_dn1(UN[3]);                \
        float xa_ = shfl_up1(XN[16]), xb_ = shfl_up1(XN[17]);               \
        float xc_ = shfl_dn1(XN[2]),  xd_ = shfl_dn1(XN[3]);                \
        if (t_ >= T0) {  /* store owned row (overlaps the shfl wait) */     \
            _Pragma("unroll")                                               \
            for (int q = 0; q < 4; ++q) {                                   \
                float4 v_;                                                  \
                v_.x = UN[2 + 4 * q]; v_.y = UN[3 + 4 * q];                 \
                v_.z = UN[4 + 4 * q]; v_.w = UN[5 + 4 * q];                 \
                *(float4*)(Ob + (size_t)t_ * HW + base + 4 * q) = v_;       \
            }                                                               \
        }                                                                   \
        SN[0]  = lo ? 0.f : sa_; SN[1]  = lo ? 0.f : sb_;                   \
        SN[18] = hi ? 0.f : sc_; SN[19] = hi ? 0.f : sd_;                   \
        UN[0]  = lo ? 0.f : ua_; UN[1]  = lo ? 0.f : ub_;                   \
        UN[18] = hi ? 0.f : uc_; UN[19] = hi ? 0.f : ud_;                   \
        XN[0]  = lo ? 0.f : xa_; XN[1]  = lo ? 0.f : xb_;                   \
        XN[18] = hi ? 0.f : xc_; XN[19] = hi ? 0.f : xd_;                   \
    }

// One wave per (batch, chunk). Chunk owns rows [T0, T0+CHUNK); warm-starts
// from zero state at g0 = max(0, T0-WARM); g0==0 chunks are exact (pre path).
// Grid (NB, NCH): linear wg id % 8 = batch -> all chunks of batch b share
// XCD b's L2 (one image = 4 MB = one XCD L2) -> warmup re-reads are L2 hits.
__global__ __launch_bounds__(64, 2) void scan_pair_wave(
    const float* __restrict__ I, float* __restrict__ O,
    const float* __restrict__ pw1, const float* __restrict__ pb1,
    const float* __restrict__ pw2, const float* __restrict__ pb2,
    const float* __restrict__ cw1, const float* __restrict__ cb1,
    const float* __restrict__ cw2, const float* __restrict__ cb2,
    int toff, int tstr)
{
    const int b     = blockIdx.x;        // batch -> XCD (linear id % 8 == b)
    const int chunk = blockIdx.y;
    const int T0 = chunk * CHUNK, T1 = T0 + CHUNK;
    const int g0 = (T0 - WARM > 0) ? (T0 - WARM) : 0;

    const int lane = threadIdx.x;        // 0..63
    const int base = lane * LPT;
    const bool lo = (lane == 0), hi = (lane == 63);

    float P1[5], P2[5], A1[5], B1[5], A2[5], B2[5];
#pragma unroll
    for (int k = 0; k < 5; ++k) {
        P1[k] = pw1[toff + k * tstr];
        P2[k] = pw2[toff + k * tstr];
        A1[k] = cw1[toff + k * tstr];
        B1[k] = cw1[25 + toff + k * tstr];
        A2[k] = cw2[toff + k * tstr];
        B2[k] = cw2[25 + toff + k * tstr];
    }
    const float pB1 = pb1[0], pB2 = pb2[0], cB1 = cb1[0], cB2 = cb2[0];

    const float* Ib = I + (size_t)b * HW * HW;
    float*       Ob = O + (size_t)b * HW * HW;

    float xeA[20], xeB[20], seA[20], seB[20], ueA[20], ueB[20];

    // ---------------- prologue ----------------
#pragma unroll
    for (int i = 0; i < 20; ++i) ueA[i] = 0.f;

    LOADX(xeB, g0);          // row g0 (consumed by s_g0 only)
    LOADX(xeA, g0 + 1);      // row g0+1 (XC for the first step)
    {
        float a0 = shfl_up1(xeB[16]), a1 = shfl_up1(xeB[17]);
        float a2 = shfl_dn1(xeB[2]),  a3 = shfl_dn1(xeB[3]);
        float b0 = shfl_up1(xeA[16]), b1 = shfl_up1(xeA[17]);
        float b2 = shfl_dn1(xeA[2]),  b3 = shfl_dn1(xeA[3]);
        xeB[0]  = lo ? 0.f : a0; xeB[1]  = lo ? 0.f : a1;
        xeB[18] = hi ? 0.f : a2; xeB[19] = hi ? 0.f : a3;
        xeA[0]  = lo ? 0.f : b0; xeA[1]  = lo ? 0.f : b1;
        xeA[18] = hi ? 0.f : b2; xeA[19] = hi ? 0.f : b3;
    }
    // s_g0 -> seA  (exact pre path at g0==0; warm path has zero state)
    if (g0 == 0) {
#pragma unroll
        for (int i = 0; i < 16; ++i) {
            float acc = pB1;
#pragma unroll
            for (int k = 0; k < 5; ++k) acc += P1[k] * xeB[i + k];
            seA[2 + i] = acc;
        }
    } else {
#pragma unroll
        for (int i = 0; i < 16; ++i) {
            float acc = cB1;
#pragma unroll
            for (int k = 0; k < 5; ++k) acc += B1[k] * xeB[i + k];
            seA[2 + i] = acc;
        }
    }
    {
        float sa = shfl_up1(seA[16]), sb = shfl_up1(seA[17]);
        float sc = shfl_dn1(seA[2]),  sd = shfl_dn1(seA[3]);
        seA[0]  = lo ? 0.f : sa; seA[1]  = lo ? 0.f : sb;
        seA[18] = hi ? 0.f : sc; seA[19] = hi ? 0.f : sd;
    }

    // ---------------- main loop ----------------
    // Invariant entering step t: XC = row t+1, SC = s_t, UC = u_{t-1}.
    // Both paths end with CUR = B holding s_{T1-1}, u_{T1-2}.
    if (g0 == 0) {
        STEP(1, 0, xeA, xeB, seA, seB, ueA, ueB);      // u_0 (pre2), s_1
        for (int t = 1; t + 1 <= T1 - 2; t += 2) {
            STEP(0, t,     xeB, xeA, seB, seA, ueB, ueA);
            STEP(0, t + 1, xeA, xeB, seA, seB, ueA, ueB);
        }
    } else {
        int t = g0;
        for (; t + 1 <= T1 - 2; t += 2) {
            STEP(0, t,     xeA, xeB, seA, seB, ueA, ueB);
            STEP(0, t + 1, xeB, xeA, seB, seA, ueB, ueA);
        }
        STEP(0, T1 - 2, xeA, xeB, seA, seB, ueA, ueB); // final odd step
    }

    // ---------------- epilogue: u_{T1-1} (always owned) ----------------
    {
        float un[16];
#pragma unroll
        for (int i = 0; i < 16; ++i) {
            float acc = cB2;
#pragma unroll
            for (int k = 0; k < 5; ++k) acc += A2[k] * ueB[i + k];
#pragma unroll
            for (int k = 0; k < 5; ++k) acc += B2[k] * seB[i + k];
            un[i] = acc;
        }
#pragma unroll
        for (int q = 0; q < 4; ++q) {
            float4 v;
            v.x = un[4 * q + 0]; v.y = un[4 * q + 1];
            v.z = un[4 * q + 2]; v.w = un[4 * q + 3];
            *(float4*)(Ob + (size_t)(T1 - 1) * HW + base + 4 * q) = v;
        }
    }
}

// out[b][c][r] = in[b][HW-1-r][c]  (transpose + reversal of the scan axis)
__global__ void transposeR_kernel(const float* __restrict__ in, float* __restrict__ out)
{
    __shared__ float tile[32][33];
    const int b  = blockIdx.z;
    const int r0 = blockIdx.y * 32;
    const int c0 = blockIdx.x * 32;
    const int tx = threadIdx.x, ty = threadIdx.y;
    const float* inb  = in  + (size_t)b * HW * HW;
    float*       outb = out + (size_t)b * HW * HW;

#pragma unroll
    for (int i = ty; i < 32; i += 8)
        tile[i][tx] = inb[(size_t)(HW - 1 - (r0 + i)) * HW + c0 + tx];
    __syncthreads();
#pragma unroll
    for (int i = ty; i < 32; i += 8)
        outb[(size_t)(c0 + i) * HW + r0 + tx] = tile[tx][i];
}

extern "C" void kernel_launch(void* const* d_in, const int* in_sizes, int n_in,
                              void* d_out, int out_size, void* d_ws, size_t ws_size,
                              hipStream_t stream)
{
    const float* x      = (const float*)d_in[0];
    const float* pre1_w = (const float*)d_in[1];
    const float* pre1_b = (const float*)d_in[2];
    const float* pre2_w = (const float*)d_in[3];
    const float* pre2_b = (const float*)d_in[4];
    const float* pre3_w = (const float*)d_in[5];
    const float* pre3_b = (const float*)d_in[6];
    const float* pre4_w = (const float*)d_in[7];
    const float* pre4_b = (const float*)d_in[8];
    const float* c1_w   = (const float*)d_in[9];
    const float* c1_b   = (const float*)d_in[10];
    const float* c2_w   = (const float*)d_in[11];
    const float* c2_b   = (const float*)d_in[12];
    const float* c3_w   = (const float*)d_in[13];
    const float* c3_b   = (const float*)d_in[14];
    const float* c4_w   = (const float*)d_in[15];
    const float* c4_b   = (const float*)d_in[16];

    float* out = (float*)d_out;   // holds T2 mid-pipeline, then final output
    float* ws  = (float*)d_ws;    // holds U, then Z (chunked scans not in-place)

    dim3 sg(NB, NCH), sb(64);     // blockIdx.x = batch -> XCD-local L2 reuse
    dim3 tg(32, 32, NB), tb(32, 8);

    // Pass 1+2 fused: scan over h, conv along w (middle-row taps off=10, str=1).
    scan_pair_wave<<<sg, sb, 0, stream>>>(
        x, ws, pre1_w, pre1_b, pre2_w, pre2_b, c1_w, c1_b, c2_w, c2_b, 10, 1);

    // T2[b][w][h] = U[b][H-1-h][w]
    transposeR_kernel<<<tg, tb, 0, stream>>>(ws, out);

    // Pass 3+4 fused: scan over w, conv along h (middle-col taps off=2, str=5).
    scan_pair_wave<<<sg, sb, 0, stream>>>(
        out, ws, pre3_w, pre3_b, pre4_w, pre4_b, c3_w, c3_b, c4_w, c4_b, 2, 5);

    // out[b][h][w] = Z[b][W-1-w][h]
    transposeR_kernel<<<tg, tb, 0, stream>>>(ws, out);
}

// Round 9
// 190.180 us; speedup vs baseline: 1.5518x; 1.0755x over previous
//
#include <hip/hip_runtime.h>

#define HW 1024
#define NB 8
#define LPT 16            // elements per lane; 64 lanes * 16 = 1024 row elements
#define CHUNK 8           // output rows owned per workgroup
#define NCH (HW / CHUNK)  // 128 chunks -> 1024 waves = 1 wave/SIMD
#define WARM 64           // warm-start window (truncation ~ rho^WARM)

__device__ __forceinline__ float shfl_up1(float v)  { return __shfl_up(v, 1, 64); }
__device__ __forceinline__ float shfl_dn1(float v)  { return __shfl_down(v, 1, 64); }

// Extended register arrays e[20]: e[2+i] = value at position base+i (i=0..15);
// e[0..1]/e[18..19] are +/-2 halos. x-halos are LOADED (aligned float2 from
// the neighboring 16-float segments -- same cache lines, no cross-lane op);
// the boundary zero-select is deferred to the CONSUMING step so the vmcnt
// wait lands a full step after issue. Only s and u use bpermute (2 groups of
// 4), each issued right after its producer conv and consumed one conv later.

#define LOADX(XD, XL, XR, T)                                                \
    {                                                                       \
        const int tr_ = ((T) < HW) ? (T) : (HW - 1);                        \
        const float* rp_ = Ib + (size_t)tr_ * HW + base;                    \
        *(float4*)&XD[2]  = ((const float4*)rp_)[0];                        \
        *(float4*)&XD[6]  = ((const float4*)rp_)[1];                        \
        *(float4*)&XD[10] = ((const float4*)rp_)[2];                        \
        *(float4*)&XD[14] = ((const float4*)rp_)[3];                        \
        XL = *(const float2*)(lo ? rp_ : rp_ - 2);   /* 8B-aligned */       \
        XR = *(const float2*)(hi ? rp_ : rp_ + 16);  /* 64B-aligned */      \
    }

#define FINX(XC, XL, XR)                                                    \
    {                                                                       \
        XC[0]  = lo ? 0.f : XL.x;  XC[1]  = lo ? 0.f : XL.y;                \
        XC[18] = hi ? 0.f : XR.x;  XC[19] = hi ? 0.f : XR.y;                \
    }

// One step at time T. XC = row T+1 (interior+raw halos), SC = s_T (ext),
// UC = u_{T-1} (ext). Writes SN = s_{T+1} (ext), UN = u_T (ext); loads row
// T+2 into XN (raw). IS_PRE2: u_0 = P2 (*) s_0 + pB2 (exact start).
#define STEP(IS_PRE2, T, XC, XCL, XCR, XN, XNL, XNR, SC, SN, UC, UN)        \
    {                                                                       \
        const int t_ = (T);                                                 \
        FINX(XC, XCL, XCR);      /* vmcnt wait: loads issued one step ago */\
        LOADX(XN, XNL, XNR, t_ + 2);   /* next row: full step of slack  */  \
        /* s_{T+1} = A1 (*) s_T + B1 (*) x_{T+1} + cB1 */                   \
        _Pragma("unroll")                                                   \
        for (int i = 0; i < 16; ++i) {                                      \
            float acc = cB1;                                                \
            _Pragma("unroll")                                               \
            for (int k = 0; k < 5; ++k) acc += A1[k] * SC[i + k];           \
            _Pragma("unroll")                                               \
            for (int k = 0; k < 5; ++k) acc += B1[k] * XC[i + k];           \
            SN[2 + i] = acc;                                                \
        }                                                                   \
        /* s-shfl group: consumed after u-conv (latency hidden) */          \
        float sa_ = shfl_up1(SN[16]), sb_ = shfl_up1(SN[17]);               \
        float sc_ = shfl_dn1(SN[2]),  sd_ = shfl_dn1(SN[3]);                \
        /* u_T = A2 (*) u_{T-1} + B2 (*) s_T + cB2  (pre: P2 (*) s_0 + pB2) */ \
        if (IS_PRE2) {                                                      \
            _Pragma("unroll")                                               \
            for (int i = 0; i < 16; ++i) {                                  \
                float acc = pB2;                                            \
                _Pragma("unroll")                                           \
                for (int k = 0; k < 5; ++k) acc += P2[k] * SC[i + k];       \
                UN[2 + i] = acc;                                            \
            }                                                               \
        } else {                                                            \
            _Pragma("unroll")                                               \
            for (int i = 0; i < 16; ++i) {                                  \
                float acc = cB2;                                            \
                _Pragma("unroll")                                           \
                for (int k = 0; k < 5; ++k) acc += A2[k] * UC[i + k];       \
                _Pragma("unroll")                                           \
                for (int k = 0; k < 5; ++k) acc += B2[k] * SC[i + k];       \
                UN[2 + i] = acc;                                            \
            }                                                               \
        }                                                                   \
        /* u-shfl group; store overlaps its latency */                      \
        float ua_ = shfl_up1(UN[16]), ub_ = shfl_up1(UN[17]);               \
        float uc_ = shfl_dn1(UN[2]),  ud_ = shfl_dn1(UN[3]);                \
        if (t_ >= T0) {                                                     \
            _Pragma("unroll")                                               \
            for (int q = 0; q < 4; ++q) {                                   \
                float4 v_;                                                  \
                v_.x = UN[2 + 4 * q]; v_.y = UN[3 + 4 * q];                 \
                v_.z = UN[4 + 4 * q]; v_.w = UN[5 + 4 * q];                 \
                *(float4*)(Ob + (size_t)t_ * HW + base + 4 * q) = v_;       \
            }                                                               \
        }                                                                   \
        SN[0]  = lo ? 0.f : sa_; SN[1]  = lo ? 0.f : sb_;                   \
        SN[18] = hi ? 0.f : sc_; SN[19] = hi ? 0.f : sd_;                   \
        UN[0]  = lo ? 0.f : ua_; UN[1]  = lo ? 0.f : ub_;                   \
        UN[18] = hi ? 0.f : uc_; UN[19] = hi ? 0.f : ud_;                   \
    }

// One wave per (batch, chunk). Chunk owns rows [T0, T0+CHUNK); warm-starts
// from zero state at g0 = max(0, T0-WARM); g0==0 chunks are exact (pre path).
// Grid (NB, NCH): linear wg id % 8 = batch -> all chunks of batch b share
// XCD b's L2 (one image = 4 MB = one XCD L2) -> warmup re-reads are L2 hits.
__global__ __launch_bounds__(64, 1) void scan_pair_wave(
    const float* __restrict__ I, float* __restrict__ O,
    const float* __restrict__ pw1, const float* __restrict__ pb1,
    const float* __restrict__ pw2, const float* __restrict__ pb2,
    const float* __restrict__ cw1, const float* __restrict__ cb1,
    const float* __restrict__ cw2, const float* __restrict__ cb2,
    int toff, int tstr)
{
    const int b     = blockIdx.x;        // batch -> XCD (linear id % 8 == b)
    const int chunk = blockIdx.y;
    const int T0 = chunk * CHUNK, T1 = T0 + CHUNK;
    const int g0 = (T0 - WARM > 0) ? (T0 - WARM) : 0;

    const int lane = threadIdx.x;        // 0..63
    const int base = lane * LPT;
    const bool lo = (lane == 0), hi = (lane == 63);

    float P1[5], P2[5], A1[5], B1[5], A2[5], B2[5];
#pragma unroll
    for (int k = 0; k < 5; ++k) {
        P1[k] = pw1[toff + k * tstr];
        P2[k] = pw2[toff + k * tstr];
        A1[k] = cw1[toff + k * tstr];
        B1[k] = cw1[25 + toff + k * tstr];
        A2[k] = cw2[toff + k * tstr];
        B2[k] = cw2[25 + toff + k * tstr];
    }
    const float pB1 = pb1[0], pB2 = pb2[0], cB1 = cb1[0], cB2 = cb2[0];

    const float* Ib = I + (size_t)b * HW * HW;
    float*       Ob = O + (size_t)b * HW * HW;

    float xeA[20], xeB[20], seA[20], seB[20], ueA[20], ueB[20];
    float2 xlA, xrA, xlB, xrB;

    // ---------------- prologue ----------------
#pragma unroll
    for (int i = 0; i < 20; ++i) ueA[i] = 0.f;

    LOADX(xeB, xlB, xrB, g0);        // row g0   (consumed by s_g0 only)
    LOADX(xeA, xlA, xrA, g0 + 1);    // row g0+1 (XC of the first step)
    FINX(xeB, xlB, xrB);
    if (g0 == 0) {      // exact start: s_0 = P1 (*) x_0 + pB1
#pragma unroll
        for (int i = 0; i < 16; ++i) {
            float acc = pB1;
#pragma unroll
            for (int k = 0; k < 5; ++k) acc += P1[k] * xeB[i + k];
            seA[2 + i] = acc;
        }
    } else {            // warm start (zero state): s_g0 = B1 (*) x_g0 + cB1
#pragma unroll
        for (int i = 0; i < 16; ++i) {
            float acc = cB1;
#pragma unroll
            for (int k = 0; k < 5; ++k) acc += B1[k] * xeB[i + k];
            seA[2 + i] = acc;
        }
    }
    {
        float sa = shfl_up1(seA[16]), sb = shfl_up1(seA[17]);
        float sc = shfl_dn1(seA[2]),  sd = shfl_dn1(seA[3]);
        seA[0]  = lo ? 0.f : sa; seA[1]  = lo ? 0.f : sb;
        seA[18] = hi ? 0.f : sc; seA[19] = hi ? 0.f : sd;
    }

    // ---------------- main loop ----------------
    // Invariant entering step t: XC = row t+1 (raw halos), SC = s_t, UC = u_{t-1}.
    // Both paths end with the B-buffers holding s_{T1-1}, u_{T1-2}.
    if (g0 == 0) {
        STEP(1, 0, xeA, xlA, xrA, xeB, xlB, xrB, seA, seB, ueA, ueB);
        for (int t = 1; t + 1 <= T1 - 2; t += 2) {
            STEP(0, t,     xeB, xlB, xrB, xeA, xlA, xrA, seB, seA, ueB, ueA);
            STEP(0, t + 1, xeA, xlA, xrA, xeB, xlB, xrB, seA, seB, ueA, ueB);
        }
    } else {
        int t = g0;
        for (; t + 1 <= T1 - 2; t += 2) {
            STEP(0, t,     xeA, xlA, xrA, xeB, xlB, xrB, seA, seB, ueA, ueB);
            STEP(0, t + 1, xeB, xlB, xrB, xeA, xlA, xrA, seB, seA, ueB, ueA);
        }
        STEP(0, T1 - 2, xeA, xlA, xrA, xeB, xlB, xrB, seA, seB, ueA, ueB);
    }

    // ---------------- epilogue: u_{T1-1} (always owned) ----------------
    {
        float un[16];
#pragma unroll
        for (int i = 0; i < 16; ++i) {
            float acc = cB2;
#pragma unroll
            for (int k = 0; k < 5; ++k) acc += A2[k] * ueB[i + k];
#pragma unroll
            for (int k = 0; k < 5; ++k) acc += B2[k] * seB[i + k];
            un[i] = acc;
        }
#pragma unroll
        for (int q = 0; q < 4; ++q) {
            float4 v;
            v.x = un[4 * q + 0]; v.y = un[4 * q + 1];
            v.z = un[4 * q + 2]; v.w = un[4 * q + 3];
            *(float4*)(Ob + (size_t)(T1 - 1) * HW + base + 4 * q) = v;
        }
    }
}

// out[b][c][r] = in[b][HW-1-r][c]  (transpose + reversal of the scan axis)
__global__ void transposeR_kernel(const float* __restrict__ in, float* __restrict__ out)
{
    __shared__ float tile[32][33];
    const int b  = blockIdx.z;
    const int r0 = blockIdx.y * 32;
    const int c0 = blockIdx.x * 32;
    const int tx = threadIdx.x, ty = threadIdx.y;
    const float* inb  = in  + (size_t)b * HW * HW;
    float*       outb = out + (size_t)b * HW * HW;

#pragma unroll
    for (int i = ty; i < 32; i += 8)
        tile[i][tx] = inb[(size_t)(HW - 1 - (r0 + i)) * HW + c0 + tx];
    __syncthreads();
#pragma unroll
    for (int i = ty; i < 32; i += 8)
        outb[(size_t)(c0 + i) * HW + r0 + tx] = tile[tx][i];
}

extern "C" void kernel_launch(void* const* d_in, const int* in_sizes, int n_in,
                              void* d_out, int out_size, void* d_ws, size_t ws_size,
                              hipStream_t stream)
{
    const float* x      = (const float*)d_in[0];
    const float* pre1_w = (const float*)d_in[1];
    const float* pre1_b = (const float*)d_in[2];
    const float* pre2_w = (const float*)d_in[3];
    const float* pre2_b = (const float*)d_in[4];
    const float* pre3_w = (const float*)d_in[5];
    const float* pre3_b = (const float*)d_in[6];
    const float* pre4_w = (const float*)d_in[7];
    const float* pre4_b = (const float*)d_in[8];
    const float* c1_w   = (const float*)d_in[9];
    const float* c1_b   = (const float*)d_in[10];
    const float* c2_w   = (const float*)d_in[11];
    const float* c2_b   = (const float*)d_in[12];
    const float* c3_w   = (const float*)d_in[13];
    const float* c3_b   = (const float*)d_in[14];
    const float* c4_w   = (const float*)d_in[15];
    const float* c4_b   = (const float*)d_in[16];

    float* out = (float*)d_out;   // holds T2 mid-pipeline, then final output
    float* ws  = (float*)d_ws;    // holds U, then Z (chunked scans not in-place)

    dim3 sg(NB, NCH), sb(64);     // blockIdx.x = batch -> XCD-local L2 reuse
    dim3 tg(32, 32, NB), tb(32, 8);

    // Pass 1+2 fused: scan over h, conv along w (middle-row taps off=10, str=1).
    scan_pair_wave<<<sg, sb, 0, stream>>>(
        x, ws, pre1_w, pre1_b, pre2_w, pre2_b, c1_w, c1_b, c2_w, c2_b, 10, 1);

    // T2[b][w][h] = U[b][H-1-h][w]
    transposeR_kernel<<<tg, tb, 0, stream>>>(ws, out);

    // Pass 3+4 fused: scan over w, conv along h (middle-col taps off=2, str=5).
    scan_pair_wave<<<sg, sb, 0, stream>>>(
        out, ws, pre3_w, pre3_b, pre4_w, pre4_b, c3_w, c3_b, c4_w, c4_b, 2, 5);

    // out[b][h][w] = Z[b][W-1-w][h]
    transposeR_kernel<<<tg, tb, 0, stream>>>(ws, out);
}

// Round 10
// 186.664 us; speedup vs baseline: 1.5810x; 1.0188x over previous
//
#include <hip/hip_runtime.h>

#define HW 1024
#define NB 8
#define LPT 16            // elements per lane; 64 lanes * 16 = 1024 row elements
#define CHUNK 8           // output rows owned per workgroup
#define NCH (HW / CHUNK)  // 128 chunks -> 1024 waves = 1 wave/SIMD
#define WARM 64           // warm-start window (truncation ~ rho^WARM)

// Whole-wave single-lane shifts via DPP (VALU, no LDS pipe, no lgkmcnt).
// bound_ctrl:0 (flag=true) => out-of-wave source reads 0, which IS the
// 'same'-padding zero at row ends (row == wave here). ROW_SHR:n = data from
// lane i-n (cf. LLVM AMDGPUAtomicOptimizer scan), so:
//   up1 (lane i <- i-1): wave_shr:1 = 0x138 ; dn1 (lane i <- i+1): wave_shl:1 = 0x130
__device__ __forceinline__ float dpp_up1(float v) {
    return __int_as_float(__builtin_amdgcn_update_dpp(
        0, __float_as_int(v), 0x138, 0xf, 0xf, true));
}
__device__ __forceinline__ float dpp_dn1(float v) {
    return __int_as_float(__builtin_amdgcn_update_dpp(
        0, __float_as_int(v), 0x130, 0xf, 0xf, true));
}

// Extended register arrays e[20]: e[2+i] = value at position base+i (i=0..15);
// e[0..1]/e[18..19] are +/-2 halos, filled by 4 DPP movs per array per step.

#define LOADX(XD, T)                                                        \
    {                                                                       \
        const int tr_ = ((T) < HW) ? (T) : (HW - 1);                        \
        const float* rp_ = Ib + (size_t)tr_ * HW + base;                    \
        *(float4*)&XD[2]  = ((const float4*)rp_)[0];                        \
        *(float4*)&XD[6]  = ((const float4*)rp_)[1];                        \
        *(float4*)&XD[10] = ((const float4*)rp_)[2];                        \
        *(float4*)&XD[14] = ((const float4*)rp_)[3];                        \
    }

// One step at time T. XC = row T+1 (interior; halos DPP'd here), SC = s_T
// (ext), UC = u_{T-1} (ext). Writes SN = s_{T+1} (ext), UN = u_T (ext);
// loads row T+2 into XN. IS_PRE2: u_0 = P2 (*) s_0 + pB2 (exact start).
#define STEP(IS_PRE2, T, XC, XN, SC, SN, UC, UN)                            \
    {                                                                       \
        const int t_ = (T);                                                 \
        /* x halos via DPP (XC interior loaded one step ago) */             \
        XC[0]  = dpp_up1(XC[16]); XC[1]  = dpp_up1(XC[17]);                 \
        XC[18] = dpp_dn1(XC[2]);  XC[19] = dpp_dn1(XC[3]);                  \
        LOADX(XN, t_ + 2);   /* next row: a full step of slack */           \
        /* s_{T+1} = A1 (*) s_T + B1 (*) x_{T+1} + cB1 */                   \
        _Pragma("unroll")                                                   \
        for (int i = 0; i < 16; ++i) {                                      \
            float acc = cB1;                                                \
            _Pragma("unroll")                                               \
            for (int k = 0; k < 5; ++k) acc += A1[k] * SC[i + k];           \
            _Pragma("unroll")                                               \
            for (int k = 0; k < 5; ++k) acc += B1[k] * XC[i + k];           \
            SN[2 + i] = acc;                                                \
        }                                                                   \
        SN[0]  = dpp_up1(SN[16]); SN[1]  = dpp_up1(SN[17]);                 \
        SN[18] = dpp_dn1(SN[2]);  SN[19] = dpp_dn1(SN[3]);                  \
        /* u_T = A2 (*) u_{T-1} + B2 (*) s_T + cB2  (pre: P2 (*) s_0 + pB2) */ \
        if (IS_PRE2) {                                                      \
            _Pragma("unroll")                                               \
            for (int i = 0; i < 16; ++i) {                                  \
                float acc = pB2;                                            \
                _Pragma("unroll")                                           \
                for (int k = 0; k < 5; ++k) acc += P2[k] * SC[i + k];       \
                UN[2 + i] = acc;                                            \
            }                                                               \
        } else {                                                            \
            _Pragma("unroll")                                               \
            for (int i = 0; i < 16; ++i) {                                  \
                float acc = cB2;                                            \
                _Pragma("unroll")                                           \
                for (int k = 0; k < 5; ++k) acc += A2[k] * UC[i + k];       \
                _Pragma("unroll")                                           \
                for (int k = 0; k < 5; ++k) acc += B2[k] * SC[i + k];       \
                UN[2 + i] = acc;                                            \
            }                                                               \
        }                                                                   \
        UN[0]  = dpp_up1(UN[16]); UN[1]  = dpp_up1(UN[17]);                 \
        UN[18] = dpp_dn1(UN[2]);  UN[19] = dpp_dn1(UN[3]);                  \
        if (t_ >= T0) {                                                     \
            _Pragma("unroll")                                               \
            for (int q = 0; q < 4; ++q) {                                   \
                float4 v_;                                                  \
                v_.x = UN[2 + 4 * q]; v_.y = UN[3 + 4 * q];                 \
                v_.z = UN[4 + 4 * q]; v_.w = UN[5 + 4 * q];                 \
                *(float4*)(Ob + (size_t)t_ * HW + base + 4 * q) = v_;       \
            }                                                               \
        }                                                                   \
    }

// One wave per (batch, chunk). Chunk owns rows [T0, T0+CHUNK); warm-starts
// from zero state at g0 = max(0, T0-WARM); g0==0 chunks are exact (pre path).
// Grid (NB, NCH): linear wg id % 8 = batch -> all chunks of batch b share
// XCD b's L2 (one image = 4 MB = one XCD L2) -> warmup re-reads are L2 hits.
__global__ __launch_bounds__(64, 1) void scan_pair_wave(
    const float* __restrict__ I, float* __restrict__ O,
    const float* __restrict__ pw1, const float* __restrict__ pb1,
    const float* __restrict__ pw2, const float* __restrict__ pb2,
    const float* __restrict__ cw1, const float* __restrict__ cb1,
    const float* __restrict__ cw2, const float* __restrict__ cb2,
    int toff, int tstr)
{
    const int b     = blockIdx.x;        // batch -> XCD (linear id % 8 == b)
    const int chunk = blockIdx.y;
    const int T0 = chunk * CHUNK, T1 = T0 + CHUNK;
    const int g0 = (T0 - WARM > 0) ? (T0 - WARM) : 0;

    const int lane = threadIdx.x;        // 0..63
    const int base = lane * LPT;

    float P1[5], P2[5], A1[5], B1[5], A2[5], B2[5];
#pragma unroll
    for (int k = 0; k < 5; ++k) {
        P1[k] = pw1[toff + k * tstr];
        P2[k] = pw2[toff + k * tstr];
        A1[k] = cw1[toff + k * tstr];
        B1[k] = cw1[25 + toff + k * tstr];
        A2[k] = cw2[toff + k * tstr];
        B2[k] = cw2[25 + toff + k * tstr];
    }
    const float pB1 = pb1[0], pB2 = pb2[0], cB1 = cb1[0], cB2 = cb2[0];

    const float* Ib = I + (size_t)b * HW * HW;
    float*       Ob = O + (size_t)b * HW * HW;

    float xeA[20], xeB[20], seA[20], seB[20], ueA[20], ueB[20];

    // ---------------- prologue ----------------
#pragma unroll
    for (int i = 0; i < 20; ++i) ueA[i] = 0.f;

    LOADX(xeB, g0);          // row g0   (consumed by s_g0 only)
    LOADX(xeA, g0 + 1);      // row g0+1 (XC of the first step)
    xeB[0]  = dpp_up1(xeB[16]); xeB[1]  = dpp_up1(xeB[17]);
    xeB[18] = dpp_dn1(xeB[2]);  xeB[19] = dpp_dn1(xeB[3]);
    if (g0 == 0) {      // exact start: s_0 = P1 (*) x_0 + pB1
#pragma unroll
        for (int i = 0; i < 16; ++i) {
            float acc = pB1;
#pragma unroll
            for (int k = 0; k < 5; ++k) acc += P1[k] * xeB[i + k];
            seA[2 + i] = acc;
        }
    } else {            // warm start (zero state): s_g0 = B1 (*) x_g0 + cB1
#pragma unroll
        for (int i = 0; i < 16; ++i) {
            float acc = cB1;
#pragma unroll
            for (int k = 0; k < 5; ++k) acc += B1[k] * xeB[i + k];
            seA[2 + i] = acc;
        }
    }
    seA[0]  = dpp_up1(seA[16]); seA[1]  = dpp_up1(seA[17]);
    seA[18] = dpp_dn1(seA[2]);  seA[19] = dpp_dn1(seA[3]);

    // ---------------- main loop ----------------
    // Invariant entering step t: XC = row t+1 (interior), SC = s_t, UC = u_{t-1}.
    // Both paths end with the B-buffers holding s_{T1-1}, u_{T1-2}.
    if (g0 == 0) {
        STEP(1, 0, xeA, xeB, seA, seB, ueA, ueB);
        for (int t = 1; t + 1 <= T1 - 2; t += 2) {
            STEP(0, t,     xeB, xeA, seB, seA, ueB, ueA);
            STEP(0, t + 1, xeA, xeB, seA, seB, ueA, ueB);
        }
    } else {
        int t = g0;
        for (; t + 1 <= T1 - 2; t += 2) {
            STEP(0, t,     xeA, xeB, seA, seB, ueA, ueB);
            STEP(0, t + 1, xeB, xeA, seB, seA, ueB, ueA);
        }
        STEP(0, T1 - 2, xeA, xeB, seA, seB, ueA, ueB);
    }

    // ---------------- epilogue: u_{T1-1} (always owned) ----------------
    {
        float un[16];
#pragma unroll
        for (int i = 0; i < 16; ++i) {
            float acc = cB2;
#pragma unroll
            for (int k = 0; k < 5; ++k) acc += A2[k] * ueB[i + k];
#pragma unroll
            for (int k = 0; k < 5; ++k) acc += B2[k] * seB[i + k];
            un[i] = acc;
        }
#pragma unroll
        for (int q = 0; q < 4; ++q) {
            float4 v;
            v.x = un[4 * q + 0]; v.y = un[4 * q + 1];
            v.z = un[4 * q + 2]; v.w = un[4 * q + 3];
            *(float4*)(Ob + (size_t)(T1 - 1) * HW + base + 4 * q) = v;
        }
    }
}

// out[b][c][r] = in[b][HW-1-r][c]  (transpose + reversal of the scan axis)
__global__ void transposeR_kernel(const float* __restrict__ in, float* __restrict__ out)
{
    __shared__ float tile[32][33];
    const int b  = blockIdx.z;
    const int r0 = blockIdx.y * 32;
    const int c0 = blockIdx.x * 32;
    const int tx = threadIdx.x, ty = threadIdx.y;
    const float* inb  = in  + (size_t)b * HW * HW;
    float*       outb = out + (size_t)b * HW * HW;

#pragma unroll
    for (int i = ty; i < 32; i += 8)
        tile[i][tx] = inb[(size_t)(HW - 1 - (r0 + i)) * HW + c0 + tx];
    __syncthreads();
#pragma unroll
    for (int i = ty; i < 32; i += 8)
        outb[(size_t)(c0 + i) * HW + r0 + tx] = tile[tx][i];
}

extern "C" void kernel_launch(void* const* d_in, const int* in_sizes, int n_in,
                              void* d_out, int out_size, void* d_ws, size_t ws_size,
                              hipStream_t stream)
{
    const float* x      = (const float*)d_in[0];
    const float* pre1_w = (const float*)d_in[1];
    const float* pre1_b = (const float*)d_in[2];
    const float* pre2_w = (const float*)d_in[3];
    const float* pre2_b = (const float*)d_in[4];
    const float* pre3_w = (const float*)d_in[5];
    const float* pre3_b = (const float*)d_in[6];
    const float* pre4_w = (const float*)d_in[7];
    const float* pre4_b = (const float*)d_in[8];
    const float* c1_w   = (const float*)d_in[9];
    const float* c1_b   = (const float*)d_in[10];
    const float* c2_w   = (const float*)d_in[11];
    const float* c2_b   = (const float*)d_in[12];
    const float* c3_w   = (const float*)d_in[13];
    const float* c3_b   = (const float*)d_in[14];
    const float* c4_w   = (const float*)d_in[15];
    const float* c4_b   = (const float*)d_in[16];

    float* out = (float*)d_out;   // holds T2 mid-pipeline, then final output
    float* ws  = (float*)d_ws;    // holds U, then Z (chunked scans not in-place)

    dim3 sg(NB, NCH), sb(64);     // blockIdx.x = batch -> XCD-local L2 reuse
    dim3 tg(32, 32, NB), tb(32, 8);

    // Pass 1+2 fused: scan over h, conv along w (middle-row taps off=10, str=1).
    scan_pair_wave<<<sg, sb, 0, stream>>>(
        x, ws, pre1_w, pre1_b, pre2_w, pre2_b, c1_w, c1_b, c2_w, c2_b, 10, 1);

    // T2[b][w][h] = U[b][H-1-h][w]
    transposeR_kernel<<<tg, tb, 0, stream>>>(ws, out);

    // Pass 3+4 fused: scan over w, conv along h (middle-col taps off=2, str=5).
    scan_pair_wave<<<sg, sb, 0, stream>>>(
        out, ws, pre3_w, pre3_b, pre4_w, pre4_b, c3_w, c3_b, c4_w, c4_b, 2, 5);

    // out[b][h][w] = Z[b][W-1-w][h]
    transposeR_kernel<<<tg, tb, 0, stream>>>(ws, out);
}

// Round 11
// 181.717 us; speedup vs baseline: 1.6240x; 1.0272x over previous
//
#include <hip/hip_runtime.h>

#define HW 1024
#define NB 8
#define LPT 16            // elements per lane; 64 lanes * 16 = 1024 row elements
#define CHUNK 8           // output rows owned per workgroup
#define NCH (HW / CHUNK)  // 128 chunks -> 1024 waves = 1 wave/SIMD
#define WARM 64           // warm-start window (truncation ~ rho^WARM)

// Whole-wave single-lane shifts via DPP (VALU pipe, no LDS/lgkmcnt).
// bound_ctrl:0 => out-of-wave source reads 0 == the 'same'-padding zero.
__device__ __forceinline__ float dpp_up1(float v) {
    return __int_as_float(__builtin_amdgcn_update_dpp(
        0, __float_as_int(v), 0x138, 0xf, 0xf, true));   // wave_shr:1
}
__device__ __forceinline__ float dpp_dn1(float v) {
    return __int_as_float(__builtin_amdgcn_update_dpp(
        0, __float_as_int(v), 0x130, 0xf, 0xf, true));   // wave_shl:1
}

// Extended register arrays e[20]: e[2+i] = value at position base+i (i=0..15);
// e[0..1]/e[18..19] are +/-2 halos (DPP-filled).
// FOUR rotating x-buffers: the load of row t+3 issued at step t is consumed
// (halo-DPP + s-conv) at step t+2 -> guaranteed 2 full steps of slack for
// vmem latency regardless of scheduler placement.

#define LOADX(XD, T)                                                        \
    {                                                                       \
        const int tr_ = ((T) < HW) ? (T) : (HW - 1);                        \
        const float* rp_ = Ib + (size_t)tr_ * HW + base;                    \
        *(float4*)&XD[2]  = ((const float4*)rp_)[0];                        \
        *(float4*)&XD[6]  = ((const float4*)rp_)[1];                        \
        *(float4*)&XD[10] = ((const float4*)rp_)[2];                        \
        *(float4*)&XD[14] = ((const float4*)rp_)[3];                        \
    }

// One step at time T. XC = row T+1 (loaded 2 steps ago), SC = s_T (ext),
// UC = u_{T-1} (ext). Writes SN = s_{T+1}, UN = u_T; loads row T+3 into XL.
#define STEP(IS_PRE2, T, XC, XL, SC, SN, UC, UN)                            \
    {                                                                       \
        const int t_ = (T);                                                 \
        XC[0]  = dpp_up1(XC[16]); XC[1]  = dpp_up1(XC[17]);                 \
        XC[18] = dpp_dn1(XC[2]);  XC[19] = dpp_dn1(XC[3]);                  \
        LOADX(XL, t_ + 3);                                                  \
        /* s_{T+1} = A1 (*) s_T + B1 (*) x_{T+1} + cB1 */                   \
        _Pragma("unroll")                                                   \
        for (int i = 0; i < 16; ++i) {                                      \
            float acc = cB1;                                                \
            _Pragma("unroll")                                               \
            for (int k = 0; k < 5; ++k) acc += A1[k] * SC[i + k];           \
            _Pragma("unroll")                                               \
            for (int k = 0; k < 5; ++k) acc += B1[k] * XC[i + k];           \
            SN[2 + i] = acc;                                                \
        }                                                                   \
        SN[0]  = dpp_up1(SN[16]); SN[1]  = dpp_up1(SN[17]);                 \
        SN[18] = dpp_dn1(SN[2]);  SN[19] = dpp_dn1(SN[3]);                  \
        /* u_T = A2 (*) u_{T-1} + B2 (*) s_T + cB2  (pre: P2 (*) s_0 + pB2) */ \
        if (IS_PRE2) {                                                      \
            _Pragma("unroll")                                               \
            for (int i = 0; i < 16; ++i) {                                  \
                float acc = pB2;                                            \
                _Pragma("unroll")                                           \
                for (int k = 0; k < 5; ++k) acc += P2[k] * SC[i + k];       \
                UN[2 + i] = acc;                                            \
            }                                                               \
        } else {                                                            \
            _Pragma("unroll")                                               \
            for (int i = 0; i < 16; ++i) {                                  \
                float acc = cB2;                                            \
                _Pragma("unroll")                                           \
                for (int k = 0; k < 5; ++k) acc += A2[k] * UC[i + k];       \
                _Pragma("unroll")                                           \
                for (int k = 0; k < 5; ++k) acc += B2[k] * SC[i + k];       \
                UN[2 + i] = acc;                                            \
            }                                                               \
        }                                                                   \
        UN[0]  = dpp_up1(UN[16]); UN[1]  = dpp_up1(UN[17]);                 \
        UN[18] = dpp_dn1(UN[2]);  UN[19] = dpp_dn1(UN[3]);                  \
        if (t_ >= T0) {                                                     \
            _Pragma("unroll")                                               \
            for (int q = 0; q < 4; ++q) {                                   \
                float4 v_;                                                  \
                v_.x = UN[2 + 4 * q]; v_.y = UN[3 + 4 * q];                 \
                v_.z = UN[4 + 4 * q]; v_.w = UN[5 + 4 * q];                 \
                *(float4*)(Ob + (size_t)t_ * HW + base + 4 * q) = v_;       \
            }                                                               \
        }                                                                   \
    }

// One wave per (batch, chunk). Chunk owns rows [T0, T0+CHUNK); warm-starts
// from zero state at g0 = max(0, T0-WARM); g0==0 chunks are exact (pre path).
// Step index i = t-g0: 3 peeled singles (i=0..2) + uniform unroll-4 loop
// (main-step count == 3 mod 4 for every chunk since T0 == 0 mod 8, WARM == 0
// mod 4). Grid (NB, NCH): wg id % 8 = batch -> XCD-local L2 reuse.
__global__ __launch_bounds__(64, 1) void scan_pair_wave(
    const float* __restrict__ I, float* __restrict__ O,
    const float* __restrict__ pw1, const float* __restrict__ pb1,
    const float* __restrict__ pw2, const float* __restrict__ pb2,
    const float* __restrict__ cw1, const float* __restrict__ cb1,
    const float* __restrict__ cw2, const float* __restrict__ cb2,
    int toff, int tstr)
{
    const int b     = blockIdx.x;        // batch -> XCD (linear id % 8 == b)
    const int chunk = blockIdx.y;
    const int T0 = chunk * CHUNK, T1 = T0 + CHUNK;
    const int g0 = (T0 - WARM > 0) ? (T0 - WARM) : 0;

    const int lane = threadIdx.x;        // 0..63
    const int base = lane * LPT;

    float P1[5], P2[5], A1[5], B1[5], A2[5], B2[5];
#pragma unroll
    for (int k = 0; k < 5; ++k) {
        P1[k] = pw1[toff + k * tstr];
        P2[k] = pw2[toff + k * tstr];
        A1[k] = cw1[toff + k * tstr];
        B1[k] = cw1[25 + toff + k * tstr];
        A2[k] = cw2[toff + k * tstr];
        B2[k] = cw2[25 + toff + k * tstr];
    }
    const float pB1 = pb1[0], pB2 = pb2[0], cB1 = cb1[0], cB2 = cb2[0];

    const float* Ib = I + (size_t)b * HW * HW;
    float*       Ob = O + (size_t)b * HW * HW;

    float xe0[20], xe1[20], xe2[20], xe3[20];
    float seA[20], seB[20], ueA[20], ueB[20];

    // ---------------- prologue ----------------
#pragma unroll
    for (int i = 0; i < 20; ++i) ueA[i] = 0.f;   // u_{g0-1} = 0 (warm start)

    LOADX(xe3, g0);          // row g0   (consumed by s_g0 only)
    LOADX(xe0, g0 + 1);      // row g0+1 (XC of step i=0)
    LOADX(xe1, g0 + 2);      // row g0+2 (XC of step i=1)
    xe3[0]  = dpp_up1(xe3[16]); xe3[1]  = dpp_up1(xe3[17]);
    xe3[18] = dpp_dn1(xe3[2]);  xe3[19] = dpp_dn1(xe3[3]);
    if (g0 == 0) {      // exact start: s_0 = P1 (*) x_0 + pB1
#pragma unroll
        for (int i = 0; i < 16; ++i) {
            float acc = pB1;
#pragma unroll
            for (int k = 0; k < 5; ++k) acc += P1[k] * xe3[i + k];
            seA[2 + i] = acc;
        }
    } else {            // warm start (zero state): s_g0 = B1 (*) x_g0 + cB1
#pragma unroll
        for (int i = 0; i < 16; ++i) {
            float acc = cB1;
#pragma unroll
            for (int k = 0; k < 5; ++k) acc += B1[k] * xe3[i + k];
            seA[2 + i] = acc;
        }
    }
    seA[0]  = dpp_up1(seA[16]); seA[1]  = dpp_up1(seA[17]);
    seA[18] = dpp_dn1(seA[2]);  seA[19] = dpp_dn1(seA[3]);

    // ---------------- 3 peeled singles (i = 0,1,2) ----------------
    STEP((g0 == 0), g0,     xe0, xe2, seA, seB, ueA, ueB);
    STEP(0,         g0 + 1, xe1, xe3, seB, seA, ueB, ueA);
    STEP(0,         g0 + 2, xe2, xe0, seA, seB, ueA, ueB);

    // ---------------- unroll-4 main loop ----------------
    for (int tt = g0 + 3; tt + 3 <= T1 - 2; tt += 4) {
        STEP(0, tt,     xe3, xe1, seB, seA, ueB, ueA);
        STEP(0, tt + 1, xe0, xe2, seA, seB, ueA, ueB);
        STEP(0, tt + 2, xe1, xe3, seB, seA, ueB, ueA);
        STEP(0, tt + 3, xe2, xe0, seA, seB, ueA, ueB);
    }

    // ---------------- epilogue: u_{T1-1} (always owned) ----------------
    {
        float un[16];
#pragma unroll
        for (int i = 0; i < 16; ++i) {
            float acc = cB2;
#pragma unroll
            for (int k = 0; k < 5; ++k) acc += A2[k] * ueB[i + k];
#pragma unroll
            for (int k = 0; k < 5; ++k) acc += B2[k] * seB[i + k];
            un[i] = acc;
        }
#pragma unroll
        for (int q = 0; q < 4; ++q) {
            float4 v;
            v.x = un[4 * q + 0]; v.y = un[4 * q + 1];
            v.z = un[4 * q + 2]; v.w = un[4 * q + 3];
            *(float4*)(Ob + (size_t)(T1 - 1) * HW + base + 4 * q) = v;
        }
    }
}

// out[b][c][r] = in[b][HW-1-r][c]  (transpose + reversal of the scan axis)
__global__ void transposeR_kernel(const float* __restrict__ in, float* __restrict__ out)
{
    __shared__ float tile[32][33];
    const int b  = blockIdx.z;
    const int r0 = blockIdx.y * 32;
    const int c0 = blockIdx.x * 32;
    const int tx = threadIdx.x, ty = threadIdx.y;
    const float* inb  = in  + (size_t)b * HW * HW;
    float*       outb = out + (size_t)b * HW * HW;

#pragma unroll
    for (int i = ty; i < 32; i += 8)
        tile[i][tx] = inb[(size_t)(HW - 1 - (r0 + i)) * HW + c0 + tx];
    __syncthreads();
#pragma unroll
    for (int i = ty; i < 32; i += 8)
        outb[(size_t)(c0 + i) * HW + r0 + tx] = tile[tx][i];
}

extern "C" void kernel_launch(void* const* d_in, const int* in_sizes, int n_in,
                              void* d_out, int out_size, void* d_ws, size_t ws_size,
                              hipStream_t stream)
{
    const float* x      = (const float*)d_in[0];
    const float* pre1_w = (const float*)d_in[1];
    const float* pre1_b = (const float*)d_in[2];
    const float* pre2_w = (const float*)d_in[3];
    const float* pre2_b = (const float*)d_in[4];
    const float* pre3_w = (const float*)d_in[5];
    const float* pre3_b = (const float*)d_in[6];
    const float* pre4_w = (const float*)d_in[7];
    const float* pre4_b = (const float*)d_in[8];
    const float* c1_w   = (const float*)d_in[9];
    const float* c1_b   = (const float*)d_in[10];
    const float* c2_w   = (const float*)d_in[11];
    const float* c2_b   = (const float*)d_in[12];
    const float* c3_w   = (const float*)d_in[13];
    const float* c3_b   = (const float*)d_in[14];
    const float* c4_w   = (const float*)d_in[15];
    const float* c4_b   = (const float*)d_in[16];

    float* out = (float*)d_out;   // holds T2 mid-pipeline, then final output
    float* ws  = (float*)d_ws;    // holds U, then Z (chunked scans not in-place)

    dim3 sg(NB, NCH), sb(64);     // blockIdx.x = batch -> XCD-local L2 reuse
    dim3 tg(32, 32, NB), tb(32, 8);

    // Pass 1+2 fused: scan over h, conv along w (middle-row taps off=10, str=1).
    scan_pair_wave<<<sg, sb, 0, stream>>>(
        x, ws, pre1_w, pre1_b, pre2_w, pre2_b, c1_w, c1_b, c2_w, c2_b, 10, 1);

    // T2[b][w][h] = U[b][H-1-h][w]
    transposeR_kernel<<<tg, tb, 0, stream>>>(ws, out);

    // Pass 3+4 fused: scan over w, conv along h (middle-col taps off=2, str=5).
    scan_pair_wave<<<sg, sb, 0, stream>>>(
        out, ws, pre3_w, pre3_b, pre4_w, pre4_b, c3_w, c3_b, c4_w, c4_b, 2, 5);

    // out[b][h][w] = Z[b][W-1-w][h]
    transposeR_kernel<<<tg, tb, 0, stream>>>(ws, out);
}